// Round 4
// baseline (169.233 us; speedup 1.0000x reference)
//
#include <hip/hip_runtime.h>

// Additive attention, factored:
//   scores[b,q,k] = sum_h w_h * tanh(qp+kp) ;  tanh(x) = 1 - 2/(1+e^{2x})
//   e^{2(qp+kp)} = Eq*Ek  (Eq=e^{2qp}, Ek=e^{2kp} precomputed)
// With a = sum_h w_h/(1+Eq*Ek): score = const - 2a, and softmax(const-2a) =
// softmax_min(a) i.e. p = exp2((min_a - a)*2*log2e). So the score loop is
// exactly fma+rcp+fma per (q,k,h) and the -2 never appears.
//
// K0: repack W -> W4T[g][h] float4 (g = d/4).
// K1: proj+exp, d-chunked: X (4KB) and W (32KB, SoA) staged in LDS per chunk.
// K2: fused scores + masked softmax + P@V per (b, 2q). eq/wv via scalar loads.

#define Bb 8
#define Qn 256
#define Kk 1024
#define Dd 256
#define Hh 128
#define DVv 128

__device__ __forceinline__ float fexp2(float x) { return __builtin_amdgcn_exp2f(x); }
__device__ __forceinline__ float frcp(float x)  { return __builtin_amdgcn_rcpf(x); }

// ---------------------------------------------------------------------------
// K0: W [H][D] -> W4T [D/4][H] float4. 64 blocks x 256 threads.
// ---------------------------------------------------------------------------
__global__ __launch_bounds__(256)
void repack_w(const float* __restrict__ Wq, const float* __restrict__ Wk,
              float4* __restrict__ Wq4T, float4* __restrict__ Wk4T)
{
    const int blk = blockIdx.x;
    const float* src = (blk < 32) ? Wq : Wk;
    float4*      dst = (blk < 32) ? Wq4T : Wk4T;
    const int idx = (blk & 31) * 256 + threadIdx.x;   // 8192 float4 per matrix
    const int g = idx >> 7;
    const int h = idx & 127;
    dst[idx] = *(const float4*)(src + (size_t)h * Dd + g * 4);
}

// ---------------------------------------------------------------------------
// K1: EqT[b][h][r] = exp2(2*log2e * X[r]·W[h]).
// 640 blocks x 256 threads; block = 16 rows x 128 h; thread = 4 rows x 2 h.
// Per 64-d chunk: stage X-tile (4 KB) + W-tile (32 KB, SoA -> conflict-free).
// Wave = 1 row-group x 64 h-groups: X reads are wave-uniform broadcasts.
// ---------------------------------------------------------------------------
__global__ __launch_bounds__(256)
void proj_exp_kernel(const float* __restrict__ queries,
                     const float* __restrict__ keys,
                     const float4* __restrict__ Wq4T,
                     const float4* __restrict__ Wk4T,
                     float* __restrict__ EqT,
                     float* __restrict__ EkT)
{
    __shared__ float Xs[16 * 64];        // 4 KB   [row][d-in-chunk]
    __shared__ float Ws[4][16 * 128];    // 32 KB  [c][g-in-chunk*128 + h]

    const int blk = blockIdx.x;          // 0..127 queries, 128..639 keys
    const float* X; const float4* W4; float* outT; int RB; int i0;
    if (blk < 128) { X = queries; W4 = Wq4T; outT = EqT; RB = Qn; i0 = blk * 16; }
    else           { X = keys;    W4 = Wk4T; outT = EkT; RB = Kk; i0 = (blk - 128) * 16; }

    const int tid  = threadIdx.x;
    const int hgrp = tid & 63;                                   // lane = h-group
    const int rgrp = __builtin_amdgcn_readfirstlane(tid >> 6);   // wave = row-group
    const int h0   = hgrp * 2;

    float acc[4][2];
#pragma unroll
    for (int i = 0; i < 4; ++i) { acc[i][0] = 0.f; acc[i][1] = 0.f; }

    for (int c0 = 0; c0 < Dd; c0 += 64) {
        const int g0 = c0 >> 2;          // 16 float4-groups per chunk
        __syncthreads();
        {   // stage X tile: 16 rows x 64 d
            const int row = tid >> 4, c4 = (tid & 15) * 4;
            *(float4*)(Xs + row * 64 + c4) =
                *(const float4*)(X + (size_t)(i0 + row) * Dd + c0 + c4);
        }
#pragma unroll
        for (int s = 0; s < 8; ++s) {    // stage W tile: 16 g x 128 h, SoA
            const int idx = tid + 256 * s;
            const int g = idx >> 7, h = idx & 127;
            const float4 w = W4[(size_t)(g0 + g) * Hh + h];
            Ws[0][g * 128 + h] = w.x;
            Ws[1][g * 128 + h] = w.y;
            Ws[2][g * 128 + h] = w.z;
            Ws[3][g * 128 + h] = w.w;
        }
        __syncthreads();

#pragma unroll 4
        for (int g = 0; g < 16; ++g) {
            float4 x[4];
#pragma unroll
            for (int i = 0; i < 4; ++i)  // wave-uniform -> broadcast
                x[i] = *(const float4*)(Xs + (rgrp * 4 + i) * 64 + g * 4);
#pragma unroll
            for (int s = 0; s < 2; ++s) {
                const int h = h0 + s;    // lane-stride 8B -> 2-way (free)
                const float wx = Ws[0][g * 128 + h];
                const float wy = Ws[1][g * 128 + h];
                const float wz = Ws[2][g * 128 + h];
                const float ww = Ws[3][g * 128 + h];
#pragma unroll
                for (int i = 0; i < 4; ++i) {
                    acc[i][s] = fmaf(x[i].x, wx, acc[i][s]);
                    acc[i][s] = fmaf(x[i].y, wy, acc[i][s]);
                    acc[i][s] = fmaf(x[i].z, wz, acc[i][s]);
                    acc[i][s] = fmaf(x[i].w, ww, acc[i][s]);
                }
            }
        }
    }

    const int b    = i0 / RB;            // 16 | RB, never straddles b
    const int rloc = (i0 % RB) + rgrp * 4;
#pragma unroll
    for (int s = 0; s < 2; ++s) {
        float4 o;
        o.x = fexp2(acc[0][s] * 2.885390082f);   // e^{2x} = 2^{2x*log2e}
        o.y = fexp2(acc[1][s] * 2.885390082f);
        o.z = fexp2(acc[2][s] * 2.885390082f);
        o.w = fexp2(acc[3][s] * 2.885390082f);
        *(float4*)(outT + (size_t)b * Hh * RB + (size_t)(h0 + s) * RB + rloc) = o;
    }
}

// ---------------------------------------------------------------------------
// K2: fused scores + masked softmax + P@V. 1024 blocks (qt<<3 | b) x 256 thr.
// Block = (b, q0..q0+1). Score: thread = 1 k x 2 q; eq2/wv wave-uniform
// s_loads, ek the only vector load; 12 VALU slots per (k,h) pair-of-q.
// Softmax: min-form (sign flip folded). PV: 8 k-slices x 32 v-lanes.
// ---------------------------------------------------------------------------
__global__ __launch_bounds__(256)
void attn_kernel(const float* __restrict__ EqT,
                 const float* __restrict__ EkT,
                 const float* __restrict__ wv,
                 const float* __restrict__ values,
                 const int* __restrict__ valid_lens,
                 float* __restrict__ out)
{
    __shared__ float2 s_p[Kk];           // 8 KB: a-scores, then softmax weights
    __shared__ float4 s_part[3][2][32];  // 3 KB: PV partials (waves 1..3)
    __shared__ float  s_inv[2];

    const int blk  = blockIdx.x;
    const int b    = blk & 7;            // fastest-varying for load balance
    const int q0   = (blk >> 3) * 2;
    const int tid  = threadIdx.x;
    const int lane = tid & 63;
    const int wave = __builtin_amdgcn_readfirstlane(tid >> 6);
    const int len  = valid_lens[b];

    const float* eqbase = EqT + (size_t)b * Hh * Qn + q0;
    const float* ekbase = EkT + (size_t)b * Hh * Kk;

    // ---- phase 1: a[q][k] = sum_h wv[h] / (1 + Eq*Ek)   (k < len)
    for (int k0 = 0; k0 < len; k0 += 256) {
        const int k = k0 + tid;
        if (k < len) {
            const float* ekp = ekbase + k;
            float a0 = 0.f, a1 = 0.f;
#pragma unroll 4
            for (int h = 0; h < Hh; ++h) {
                const float ek = ekp[(size_t)h * Kk];                 // vector
                const float w  = wv[h];                               // s_load
                const float2 eq = *(const float2*)(eqbase + (size_t)h * Qn); // s_load
                a0 = fmaf(w, frcp(fmaf(eq.x, ek, 1.0f)), a0);
                a1 = fmaf(w, frcp(fmaf(eq.y, ek, 1.0f)), a1);
            }
            s_p[k] = make_float2(a0, a1);
        }
    }
    __syncthreads();

    // ---- phase 2: softmax over -2a == min-form over a. Waves 0,1 own q=wave.
    if (wave < 2) {
        const int q = wave;
        const float* sp = (const float*)s_p;
        float mn = 3.0e38f;
        for (int i = lane; i < len; i += 64) mn = fminf(mn, sp[i * 2 + q]);
#pragma unroll
        for (int off = 32; off > 0; off >>= 1) mn = fminf(mn, __shfl_xor(mn, off));
        float sum = 0.f;
        float* spw = (float*)s_p;
        for (int i = lane; i < len; i += 64) {
            const float p = fexp2((mn - spw[i * 2 + q]) * 2.885390082f);
            spw[i * 2 + q] = p;
            sum += p;
        }
#pragma unroll
        for (int off = 32; off > 0; off >>= 1) sum += __shfl_xor(sum, off);
        if (lane == 0) s_inv[q] = frcp(sum);
    }
    __syncthreads();

    // ---- phase 3: P@V. 8 k-slices x (32 lanes x float4 = 128 v)
    {
        const int slice = tid >> 5;
        const int l32   = tid & 31;
        const int v4    = l32 << 2;
        const float* vp = values + (size_t)b * Kk * DVv + v4;
        float a[2][4];
#pragma unroll
        for (int q = 0; q < 2; ++q) { a[q][0]=0.f; a[q][1]=0.f; a[q][2]=0.f; a[q][3]=0.f; }
        for (int k = slice; k < len; k += 8) {
            const float4 val = *(const float4*)(vp + (size_t)k * DVv);
            const float2 w = s_p[k];     // 2 addrs per wave -> broadcast
            a[0][0] = fmaf(w.x, val.x, a[0][0]);
            a[0][1] = fmaf(w.x, val.y, a[0][1]);
            a[0][2] = fmaf(w.x, val.z, a[0][2]);
            a[0][3] = fmaf(w.x, val.w, a[0][3]);
            a[1][0] = fmaf(w.y, val.x, a[1][0]);
            a[1][1] = fmaf(w.y, val.y, a[1][1]);
            a[1][2] = fmaf(w.y, val.z, a[1][2]);
            a[1][3] = fmaf(w.y, val.w, a[1][3]);
        }
        // fold the two 32-lane slices within each wave
#pragma unroll
        for (int q = 0; q < 2; ++q)
#pragma unroll
            for (int x = 0; x < 4; ++x) a[q][x] += __shfl_xor(a[q][x], 32);
        if (wave > 0 && lane < 32) {
#pragma unroll
            for (int q = 0; q < 2; ++q)
                s_part[wave - 1][q][l32] = make_float4(a[q][0], a[q][1], a[q][2], a[q][3]);
        }
        __syncthreads();
        if (wave == 0 && lane < 32) {
#pragma unroll
            for (int q = 0; q < 2; ++q) {
                float r0 = a[q][0], r1 = a[q][1], r2 = a[q][2], r3 = a[q][3];
#pragma unroll
                for (int w = 0; w < 3; ++w) {
                    const float4 p = s_part[w][q][l32];
                    r0 += p.x; r1 += p.y; r2 += p.z; r3 += p.w;
                }
                const float inv = s_inv[q];
                *(float4*)(out + (size_t)(b * Qn + q0 + q) * DVv + v4) =
                    make_float4(r0 * inv, r1 * inv, r2 * inv, r3 * inv);
            }
        }
    }
}

extern "C" void kernel_launch(void* const* d_in, const int* in_sizes, int n_in,
                              void* d_out, int out_size, void* d_ws, size_t ws_size,
                              hipStream_t stream) {
    (void)in_sizes; (void)n_in; (void)out_size; (void)ws_size;
    const float* queries    = (const float*)d_in[0];
    const float* keys       = (const float*)d_in[1];
    const float* values     = (const float*)d_in[2];
    const int*   valid_lens = (const int*)  d_in[3];
    const float* Wq         = (const float*)d_in[4];
    const float* Wk         = (const float*)d_in[5];
    const float* wvv        = (const float*)d_in[6];
    float* out = (float*)d_out;

    float* Wq4T = (float*)d_ws;                                  // 256*128 floats
    float* Wk4T = Wq4T + (size_t)Dd * Hh;
    float* EqT  = Wk4T + (size_t)Dd * Hh;                        // 8*128*256
    float* EkT  = EqT + (size_t)Bb * Hh * Qn;                    // 8*128*1024

    repack_w       <<<  64, 256, 0, stream>>>(Wq, Wk, (float4*)Wq4T, (float4*)Wk4T);
    proj_exp_kernel<<< 640, 256, 0, stream>>>(queries, keys, (const float4*)Wq4T,
                                              (const float4*)Wk4T, EqT, EkT);
    attn_kernel    <<<1024, 256, 0, stream>>>(EqT, EkT, wvv, values, valid_lens, out);
}